// Round 2
// baseline (3174.604 us; speedup 1.0000x reference)
//
#include <hip/hip_runtime.h>
#include <hip/hip_bf16.h>
#include <cstdint>

#define DI __device__ __forceinline__

// ---- problem constants ----
constexpr int Bc = 2, Nc = 2048, Cc = 1024, Hc = 16, Dc = 64;
// workspace layout (floats)
constexpr size_t QOFF = 0;
constexpr size_t KOFF = (size_t)Bc * Hc * Nc * Dc;          //  4,194,304
constexpr size_t VOFF = 2 * KOFF;                           //  8,388,608
constexpr size_t ROFF = 3 * KOFF;                           // 12,582,912
constexpr size_t POFF = 4 * KOFF;                           // 16,777,216 (8 x 131072 partial states)

DI float gpow(float g, float p) {
    // g in [0,1], p >= 0 integer-valued
    if (p <= 0.f) return 1.f;
    if (g <= 0.f) return 0.f;
    return exp2f(p * log2f(g));
}

// ---------------------------------------------------------------------------
// K1: qkv = x @ W_qkv + b_qkv ; scatter to q(*scale)/k/v in [B,H,N,D] f32
// ---------------------------------------------------------------------------
__global__ __launch_bounds__(256) void qkv_gemm(
    const float* __restrict__ x,     // [4096,1024]
    const float* __restrict__ Wqkv,  // [1024,3072]
    const float* __restrict__ bqkv,  // [3072]
    float* __restrict__ q, float* __restrict__ k, float* __restrict__ v)
{
    __shared__ float Xs[64][33];
    __shared__ float Ws[32][65];
    const int tid = threadIdx.x, tx = tid & 15, ty = tid >> 4;
    const int row0 = blockIdx.y * 64, col0 = blockIdx.x * 64;
    float acc[4][4] = {};
    for (int ko = 0; ko < 1024; ko += 32) {
        {   // X tile: 64 rows x 32 k
            int r = tid >> 2, kk = (tid & 3) * 8;
            const float* xp = x + (size_t)(row0 + r) * 1024 + ko + kk;
            float4 a0 = *reinterpret_cast<const float4*>(xp);
            float4 a1 = *reinterpret_cast<const float4*>(xp + 4);
            Xs[r][kk] = a0.x; Xs[r][kk + 1] = a0.y; Xs[r][kk + 2] = a0.z; Xs[r][kk + 3] = a0.w;
            Xs[r][kk + 4] = a1.x; Xs[r][kk + 5] = a1.y; Xs[r][kk + 6] = a1.z; Xs[r][kk + 7] = a1.w;
        }
        {   // W tile: 32 k x 64 cols
            int kr = tid >> 3, c = (tid & 7) * 8;
            const float* wp = Wqkv + (size_t)(ko + kr) * 3072 + col0 + c;
            float4 a0 = *reinterpret_cast<const float4*>(wp);
            float4 a1 = *reinterpret_cast<const float4*>(wp + 4);
            Ws[kr][c] = a0.x; Ws[kr][c + 1] = a0.y; Ws[kr][c + 2] = a0.z; Ws[kr][c + 3] = a0.w;
            Ws[kr][c + 4] = a1.x; Ws[kr][c + 5] = a1.y; Ws[kr][c + 6] = a1.z; Ws[kr][c + 7] = a1.w;
        }
        __syncthreads();
        #pragma unroll
        for (int kk = 0; kk < 32; kk++) {
            float a[4], b[4];
            #pragma unroll
            for (int i = 0; i < 4; i++) a[i] = Xs[ty * 4 + i][kk];
            #pragma unroll
            for (int j = 0; j < 4; j++) b[j] = Ws[kk][tx * 4 + j];
            #pragma unroll
            for (int i = 0; i < 4; i++)
                #pragma unroll
                for (int j = 0; j < 4; j++) acc[i][j] += a[i] * b[j];
        }
        __syncthreads();
    }
    #pragma unroll
    for (int i = 0; i < 4; i++) {
        int rr = row0 + ty * 4 + i;
        int bb = rr >> 11, n = rr & 2047;
        #pragma unroll
        for (int j = 0; j < 4; j++) {
            int c = col0 + tx * 4 + j;
            float val = acc[i][j] + bqkv[c];
            int which = c >> 10, cc = c & 1023;
            int h = cc >> 6, d = cc & 63;
            size_t idx = (((size_t)(bb * Hc + h)) * Nc + n) * Dc + d;
            if (which == 0)      q[idx] = val * 0.125f;   // scale = D^-0.5
            else if (which == 1) k[idx] = val;
            else                 v[idx] = val;
        }
    }
}

// ---------------------------------------------------------------------------
// K2: per (b,h, 64-row q tile): ret = (q k^T * mask) v + gamma^pos * (q @ sp)
//     writes ret in [B,N,C] layout (c = h*64+d)
// ---------------------------------------------------------------------------
__global__ __launch_bounds__(256) void retention_kernel(
    const float* __restrict__ qg, const float* __restrict__ kg,
    const float* __restrict__ vg,
    const float* __restrict__ mask,   // [H,N,N]
    const float* __restrict__ gamma,  // [H]
    const float* __restrict__ sprev,  // [B,H,D,D]
    float* __restrict__ ret)          // [B,N,C]
{
    __shared__ float Ks[64][65];
    __shared__ float Vs[64][65];
    __shared__ float Ss[64][65];   // first state_prev, then masked scores
    const int tid = threadIdx.x;
    const int i  = tid >> 2;          // row within tile 0..63
    const int c0 = (tid & 3) * 16;    // 16-wide column group
    const int bh = blockIdx.y;        // b*16+h
    const int b = bh >> 4, h = bh & 15;
    const int n0 = blockIdx.x * 64;
    const int nrow = n0 + i;
    const float g = gamma[h];

    float qr[64];
    const float* qrow = qg + ((size_t)bh * Nc + nrow) * Dc;
    #pragma unroll
    for (int d4 = 0; d4 < 64; d4 += 4) {
        float4 t = *reinterpret_cast<const float4*>(qrow + d4);
        qr[d4] = t.x; qr[d4 + 1] = t.y; qr[d4 + 2] = t.z; qr[d4 + 3] = t.w;
    }
    {   // stage state_prev[b,h] into Ss
        const float* sp = sprev + (size_t)bh * 64 * 64 + i * 64 + c0;
        #pragma unroll
        for (int j4 = 0; j4 < 16; j4 += 4) {
            float4 t = *reinterpret_cast<const float4*>(sp + j4);
            Ss[i][c0 + j4] = t.x; Ss[i][c0 + j4 + 1] = t.y;
            Ss[i][c0 + j4 + 2] = t.z; Ss[i][c0 + j4 + 3] = t.w;
        }
    }
    __syncthreads();
    // cross term: acc[dd] = g^(nrow+1) * sum_d q[nrow,d] * sp[d, c0+dd]
    float acc[16];
    {
        float s[16] = {};
        #pragma unroll
        for (int d = 0; d < 64; d++) {
            float qv = qr[d];
            #pragma unroll
            for (int dd = 0; dd < 16; dd++) s[dd] += qv * Ss[d][c0 + dd];
        }
        float cf = gpow(g, (float)(nrow + 1));
        #pragma unroll
        for (int dd = 0; dd < 16; dd++) acc[dd] = cf * s[dd];
    }

    const float* kbase = kg + (size_t)bh * Nc * Dc;
    const float* vbase = vg + (size_t)bh * Nc * Dc;
    const float* mrow = mask + ((size_t)h * Nc + nrow) * Nc;

    for (int m0 = 0; m0 < Nc; m0 += 64) {
        __syncthreads();   // prior Ss/Vs consumers done; Ks/Vs free
        #pragma unroll
        for (int j4 = 0; j4 < 16; j4 += 4) {
            float4 tk = *reinterpret_cast<const float4*>(kbase + (size_t)(m0 + i) * 64 + c0 + j4);
            Ks[i][c0 + j4] = tk.x; Ks[i][c0 + j4 + 1] = tk.y;
            Ks[i][c0 + j4 + 2] = tk.z; Ks[i][c0 + j4 + 3] = tk.w;
            float4 tv = *reinterpret_cast<const float4*>(vbase + (size_t)(m0 + i) * 64 + c0 + j4);
            Vs[i][c0 + j4] = tv.x; Vs[i][c0 + j4 + 1] = tv.y;
            Vs[i][c0 + j4 + 2] = tv.z; Vs[i][c0 + j4 + 3] = tv.w;
        }
        __syncthreads();
        // scores S[i, c0+j] = (q . k) * mask
        float s[16] = {};
        #pragma unroll
        for (int d = 0; d < 64; d++) {
            float qv = qr[d];
            #pragma unroll
            for (int j = 0; j < 16; j++) s[j] += qv * Ks[c0 + j][d];
        }
        {
            const float* mp = mrow + m0 + c0;
            #pragma unroll
            for (int j4 = 0; j4 < 16; j4 += 4) {
                float4 mf = *reinterpret_cast<const float4*>(mp + j4);
                Ss[i][c0 + j4] = s[j4] * mf.x; Ss[i][c0 + j4 + 1] = s[j4 + 1] * mf.y;
                Ss[i][c0 + j4 + 2] = s[j4 + 2] * mf.z; Ss[i][c0 + j4 + 3] = s[j4 + 3] * mf.w;
            }
        }
        __syncthreads();
        // acc[dd] += sum_j S[i,j] * V[j, c0+dd]
        for (int j = 0; j < 64; j++) {
            float sv = Ss[i][j];
            #pragma unroll
            for (int dd = 0; dd < 16; dd++) acc[dd] += sv * Vs[j][c0 + dd];
        }
    }
    float* rp = ret + ((size_t)b * Nc + nrow) * Cc + h * 64 + c0;
    #pragma unroll
    for (int d4 = 0; d4 < 16; d4 += 4) {
        float4 t; t.x = acc[d4]; t.y = acc[d4 + 1]; t.z = acc[d4 + 2]; t.w = acc[d4 + 3];
        *reinterpret_cast<float4*>(rp + d4) = t;
    }
}

// ---------------------------------------------------------------------------
// K3a: partial state over an n-chunk of 256: sum_n g^(2047-n) k_n^T v_n
// ---------------------------------------------------------------------------
__global__ __launch_bounds__(256) void state_partial(
    const float* __restrict__ kg, const float* __restrict__ vg,
    const float* __restrict__ gamma,
    float* __restrict__ partial)   // [8][B*H*64*64]
{
    __shared__ float Ks[64][65];
    __shared__ float Vs[64][65];
    __shared__ float wdec[64];
    const int chunk = blockIdx.x;   // 0..7
    const int bh = blockIdx.y;      // 0..31
    const int h = bh & 15;
    const int tid = threadIdx.x;
    const int d = tid >> 2;         // 0..63 (also staging row)
    const int e0 = (tid & 3) * 16;
    const float g = gamma[h];
    const float* kb = kg + (size_t)bh * Nc * Dc;
    const float* vb = vg + (size_t)bh * Nc * Dc;
    float acc[16] = {};
    const int nStart = chunk * 256;
    for (int m0 = nStart; m0 < nStart + 256; m0 += 64) {
        __syncthreads();
        #pragma unroll
        for (int j4 = 0; j4 < 16; j4 += 4) {
            float4 tk = *reinterpret_cast<const float4*>(kb + (size_t)(m0 + d) * 64 + e0 + j4);
            Ks[d][e0 + j4] = tk.x; Ks[d][e0 + j4 + 1] = tk.y;
            Ks[d][e0 + j4 + 2] = tk.z; Ks[d][e0 + j4 + 3] = tk.w;
            float4 tv = *reinterpret_cast<const float4*>(vb + (size_t)(m0 + d) * 64 + e0 + j4);
            Vs[d][e0 + j4] = tv.x; Vs[d][e0 + j4 + 1] = tv.y;
            Vs[d][e0 + j4 + 2] = tv.z; Vs[d][e0 + j4 + 3] = tv.w;
        }
        if (tid < 64) wdec[tid] = gpow(g, (float)(2047 - (m0 + tid)));
        __syncthreads();
        for (int nn = 0; nn < 64; nn++) {
            float kw = Ks[nn][d] * wdec[nn];
            #pragma unroll
            for (int j = 0; j < 16; j++) acc[j] += kw * Vs[nn][e0 + j];
        }
    }
    float* pp = partial + (size_t)chunk * (Bc * Hc * Dc * Dc)
              + ((size_t)bh * 64 + d) * 64 + e0;
    #pragma unroll
    for (int j = 0; j < 16; j++) pp[j] = acc[j];
}

// K3b: state = sum_chunks partial + state_prev * g^N
__global__ __launch_bounds__(256) void state_reduce(
    const float* __restrict__ partial,
    const float* __restrict__ sprev,
    const float* __restrict__ gamma,
    float* __restrict__ outState)
{
    const int idx = blockIdx.x * 256 + threadIdx.x;   // 0..131071
    const int bh = idx >> 12;
    const int h = bh & 15;
    const float g = gamma[h];
    float acc = sprev[idx] * gpow(g, 2048.f);
    #pragma unroll
    for (int c = 0; c < 8; c++) acc += partial[(size_t)c * (Bc * Hc * Dc * Dc) + idx];
    outState[idx] = acc;
}

// ---------------------------------------------------------------------------
// K4: out = ret @ W_out + b_out
// ---------------------------------------------------------------------------
__global__ __launch_bounds__(256) void out_gemm(
    const float* __restrict__ ret,   // [4096,1024]
    const float* __restrict__ Wout,  // [1024,1024]
    const float* __restrict__ bout,  // [1024]
    float* __restrict__ out)         // [4096,1024]
{
    __shared__ float Xs[64][33];
    __shared__ float Ws[32][65];
    const int tid = threadIdx.x, tx = tid & 15, ty = tid >> 4;
    const int row0 = blockIdx.y * 64, col0 = blockIdx.x * 64;
    float acc[4][4] = {};
    for (int ko = 0; ko < 1024; ko += 32) {
        {
            int r = tid >> 2, kk = (tid & 3) * 8;
            const float* ap = ret + (size_t)(row0 + r) * 1024 + ko + kk;
            float4 a0 = *reinterpret_cast<const float4*>(ap);
            float4 a1 = *reinterpret_cast<const float4*>(ap + 4);
            Xs[r][kk] = a0.x; Xs[r][kk + 1] = a0.y; Xs[r][kk + 2] = a0.z; Xs[r][kk + 3] = a0.w;
            Xs[r][kk + 4] = a1.x; Xs[r][kk + 5] = a1.y; Xs[r][kk + 6] = a1.z; Xs[r][kk + 7] = a1.w;
        }
        {
            int kr = tid >> 3, c = (tid & 7) * 8;
            const float* wp = Wout + (size_t)(ko + kr) * 1024 + col0 + c;
            float4 a0 = *reinterpret_cast<const float4*>(wp);
            float4 a1 = *reinterpret_cast<const float4*>(wp + 4);
            Ws[kr][c] = a0.x; Ws[kr][c + 1] = a0.y; Ws[kr][c + 2] = a0.z; Ws[kr][c + 3] = a0.w;
            Ws[kr][c + 4] = a1.x; Ws[kr][c + 5] = a1.y; Ws[kr][c + 6] = a1.z; Ws[kr][c + 7] = a1.w;
        }
        __syncthreads();
        #pragma unroll
        for (int kk = 0; kk < 32; kk++) {
            float a[4], b[4];
            #pragma unroll
            for (int i = 0; i < 4; i++) a[i] = Xs[ty * 4 + i][kk];
            #pragma unroll
            for (int j = 0; j < 4; j++) b[j] = Ws[kk][tx * 4 + j];
            #pragma unroll
            for (int i = 0; i < 4; i++)
                #pragma unroll
                for (int j = 0; j < 4; j++) acc[i][j] += a[i] * b[j];
        }
        __syncthreads();
    }
    #pragma unroll
    for (int i = 0; i < 4; i++) {
        int rr = row0 + ty * 4 + i;
        #pragma unroll
        for (int j = 0; j < 4; j++) {
            int c = col0 + tx * 4 + j;
            out[(size_t)rr * 1024 + c] = acc[i][j] + bout[c];
        }
    }
}

extern "C" void kernel_launch(void* const* d_in, const int* in_sizes, int n_in,
                              void* d_out, int out_size, void* d_ws, size_t ws_size,
                              hipStream_t stream) {
    (void)in_sizes; (void)n_in; (void)out_size; (void)ws_size;
    const float* x     = (const float*)d_in[0]; // [B,N,C]
    const float* mask  = (const float*)d_in[1]; // [H,N,N]
    const float* gamma = (const float*)d_in[2]; // [H]
    const float* sprev = (const float*)d_in[3]; // [B,H,D,D]
    const float* Wqkv  = (const float*)d_in[4]; // [C,3C]
    const float* bqkv  = (const float*)d_in[5]; // [3C]
    const float* Wout  = (const float*)d_in[6]; // [C,C]
    const float* bout  = (const float*)d_in[7]; // [C]

    float* ws = (float*)d_ws;
    float* q = ws + QOFF;
    float* k = ws + KOFF;
    float* v = ws + VOFF;
    float* r = ws + ROFF;
    float* p = ws + POFF;

    float* out      = (float*)d_out;                              // [B,N,C]
    float* outState = (float*)d_out + (size_t)Bc * Nc * Cc;       // [B,H,D,D]

    qkv_gemm<<<dim3(48, 64), 256, 0, stream>>>(x, Wqkv, bqkv, q, k, v);
    retention_kernel<<<dim3(32, 32), 256, 0, stream>>>(q, k, v, mask, gamma, sprev, r);
    state_partial<<<dim3(8, 32), 256, 0, stream>>>(k, v, gamma, p);
    state_reduce<<<512, 256, 0, stream>>>(p, sprev, gamma, outState);
    out_gemm<<<dim3(16, 64), 256, 0, stream>>>(r, Wout, bout, out);
}

// Round 3
// 577.174 us; speedup vs baseline: 5.5003x; 5.5003x over previous
//
#include <hip/hip_runtime.h>
#include <hip/hip_bf16.h>
#include <cstdint>

#define DI __device__ __forceinline__

typedef __attribute__((ext_vector_type(8))) short v8s;   // 8 bf16 (4 VGPRs)
typedef __attribute__((ext_vector_type(4))) float v4f;   // 4 f32 acc

// ---- problem constants ----
constexpr int Bc = 2, Nc = 2048, Cc = 1024, Hc = 16, Dc = 64;

DI float bfbits(uint32_t u) { union { uint32_t i; float f; } c; c.i = u; return c.f; }
DI unsigned short f2bf(float f) {
    union { float f; uint32_t u; } c; c.f = f;
    uint32_t r = c.u + 0x7FFFu + ((c.u >> 16) & 1u);   // RNE
    return (unsigned short)(r >> 16);
}
DI void unpackb8(uint4 u, float* f) {
    f[0] = bfbits(u.x << 16); f[1] = bfbits(u.x & 0xFFFF0000u);
    f[2] = bfbits(u.y << 16); f[3] = bfbits(u.y & 0xFFFF0000u);
    f[4] = bfbits(u.z << 16); f[5] = bfbits(u.z & 0xFFFF0000u);
    f[6] = bfbits(u.w << 16); f[7] = bfbits(u.w & 0xFFFF0000u);
}
DI float gpow(float g, float p) {
    if (p <= 0.f) return 1.f;
    if (g <= 0.f) return 0.f;
    return exp2f(p * log2f(g));
}

// ---------------------------------------------------------------------------
// cvt: f32 -> bf16, 8 elems/thread
// ---------------------------------------------------------------------------
__global__ __launch_bounds__(256) void cvt_bf16(
    const float* __restrict__ in, unsigned short* __restrict__ out, int n8)
{
    int i = blockIdx.x * 256 + threadIdx.x;
    if (i >= n8) return;
    float4 a = ((const float4*)in)[i * 2];
    float4 b = ((const float4*)in)[i * 2 + 1];
    ushort4 r0; r0.x = f2bf(a.x); r0.y = f2bf(a.y); r0.z = f2bf(a.z); r0.w = f2bf(a.w);
    ushort4 r1; r1.x = f2bf(b.x); r1.y = f2bf(b.y); r1.z = f2bf(b.z); r1.w = f2bf(b.w);
    ((ushort4*)out)[i * 2] = r0; ((ushort4*)out)[i * 2 + 1] = r1;
}

// ---------------------------------------------------------------------------
// transpose + cvt: in f32 [R][C] -> out bf16 [C][R].  grid (C/64, R/64)
// ---------------------------------------------------------------------------
__global__ __launch_bounds__(256) void transpose_cvt(
    const float* __restrict__ in, unsigned short* __restrict__ out, int R, int C)
{
    __shared__ float T[64][65];
    const int tid = threadIdx.x;
    const int r0 = blockIdx.y * 64, c0 = blockIdx.x * 64;
    #pragma unroll
    for (int rep = 0; rep < 4; rep++) {
        int row = (tid >> 4) + rep * 16, col = (tid & 15) * 4;
        float4 v = *reinterpret_cast<const float4*>(in + (size_t)(r0 + row) * C + c0 + col);
        T[row][col] = v.x; T[row][col + 1] = v.y; T[row][col + 2] = v.z; T[row][col + 3] = v.w;
    }
    __syncthreads();
    #pragma unroll
    for (int rep = 0; rep < 4; rep++) {
        int ocr = (tid >> 4) + rep * 16, j4 = (tid & 15) * 4;
        ushort4 w;
        w.x = f2bf(T[j4][ocr]);     w.y = f2bf(T[j4 + 1][ocr]);
        w.z = f2bf(T[j4 + 2][ocr]); w.w = f2bf(T[j4 + 3][ocr]);
        *reinterpret_cast<ushort4*>(out + (size_t)(c0 + ocr) * R + r0 + j4) = w;
    }
}

// ---------------------------------------------------------------------------
// K1: qkv GEMM via MFMA.  A=xb [4096][1024] bf16, B=Wqkv^T [3072][1024] bf16.
// Epilogue scatters q(*0.125)/k/v bf16 [B,H,N,D] and v^T [B,H,D,N].
// ---------------------------------------------------------------------------
__global__ __launch_bounds__(256) void qkv_mfma(
    const unsigned short* __restrict__ A, const unsigned short* __restrict__ Bt,
    const float* __restrict__ bias,
    unsigned short* __restrict__ q, unsigned short* __restrict__ k,
    unsigned short* __restrict__ v, unsigned short* __restrict__ vt)
{
    __shared__ unsigned short As[64][72];
    __shared__ unsigned short Bs[64][72];
    const int tid = threadIdx.x, wave = tid >> 6, lane = tid & 63;
    const int L = lane & 15, quad = lane >> 4;
    const int row0 = blockIdx.y * 64, col0 = blockIdx.x * 64;
    v4f acc[4];
    #pragma unroll
    for (int s = 0; s < 4; s++) { acc[s][0] = 0.f; acc[s][1] = 0.f; acc[s][2] = 0.f; acc[s][3] = 0.f; }
    for (int k0 = 0; k0 < 1024; k0 += 64) {
        __syncthreads();
        #pragma unroll
        for (int rep = 0; rep < 2; rep++) {
            int r = (tid >> 3) + rep * 32, ch = (tid & 7) * 8;
            *(uint4*)&As[r][ch] = *(const uint4*)(A + (size_t)(row0 + r) * 1024 + k0 + ch);
            *(uint4*)&Bs[r][ch] = *(const uint4*)(Bt + (size_t)(col0 + r) * 1024 + k0 + ch);
        }
        __syncthreads();
        v8s a0 = *(v8s*)&As[wave * 16 + L][quad * 8];
        v8s a1 = *(v8s*)&As[wave * 16 + L][32 + quad * 8];
        #pragma unroll
        for (int s = 0; s < 4; s++) {
            v8s b0 = *(v8s*)&Bs[s * 16 + L][quad * 8];
            v8s b1 = *(v8s*)&Bs[s * 16 + L][32 + quad * 8];
            acc[s] = __builtin_amdgcn_mfma_f32_16x16x32_bf16(a0, b0, acc[s], 0, 0, 0);
            acc[s] = __builtin_amdgcn_mfma_f32_16x16x32_bf16(a1, b1, acc[s], 0, 0, 0);
        }
    }
    const int which = col0 >> 10;
    const int h = (col0 & 1023) >> 6;
    #pragma unroll
    for (int s = 0; s < 4; s++) {
        int c = col0 + s * 16 + L;
        int d = s * 16 + L;
        float bv = bias[c];
        #pragma unroll
        for (int reg = 0; reg < 4; reg++) {
            int rr = row0 + wave * 16 + quad * 4 + reg;
            int b = rr >> 11, n = rr & 2047;
            float val = acc[s][reg] + bv;
            size_t base = (((size_t)(b * Hc + h)) * Nc + n) * Dc + d;
            if (which == 0)      q[base] = f2bf(val * 0.125f);
            else if (which == 1) k[base] = f2bf(val);
            else {
                unsigned short bb = f2bf(val);
                v[base] = bb;
                vt[(((size_t)(b * Hc + h)) * Dc + d) * Nc + n] = bb;
            }
        }
    }
}

// ---------------------------------------------------------------------------
// K2: retention via MFMA. Per block: (b,h), 64 q-rows.
//   O = gamma^(n+1) * Q@sprev  +  sum_mtiles (Q K^T * mask) V
// ---------------------------------------------------------------------------
__global__ __launch_bounds__(256) void retention_mfma(
    const unsigned short* __restrict__ qb, const unsigned short* __restrict__ kb,
    const unsigned short* __restrict__ vtb,
    const float* __restrict__ mask, const float* __restrict__ gamma,
    const float* __restrict__ sprev,
    unsigned short* __restrict__ retb)   // [B,N,C] bf16
{
    __shared__ unsigned short Ks[64][72];   // Q tile at init, then K tiles
    __shared__ unsigned short Vt[64][72];   // V^T tiles
    __shared__ unsigned short Sm[64][72];   // sprev^T at init, then masked scores
    const int tid = threadIdx.x, wave = tid >> 6, lane = tid & 63;
    const int L = lane & 15, quad = lane >> 4;
    const int bh = blockIdx.y, b = bh >> 4, h = bh & 15;
    const int n0 = blockIdx.x * 64;
    const float g = gamma[h];

    {   // stage Q tile -> Ks ; sprev^T (bf16) -> Sm
        #pragma unroll
        for (int rep = 0; rep < 2; rep++) {
            int r = (tid >> 3) + rep * 32, ch = (tid & 7) * 8;
            *(uint4*)&Ks[r][ch] = *(const uint4*)(qb + ((size_t)bh * Nc + n0 + r) * Dc + ch);
        }
        int d = tid >> 2, e0 = (tid & 3) * 16;
        const float* sp = sprev + (size_t)bh * 4096 + d * 64 + e0;
        #pragma unroll
        for (int j = 0; j < 16; j++) Sm[e0 + j][d] = f2bf(sp[j]);
    }
    __syncthreads();
    const v8s qf0 = *(v8s*)&Ks[wave * 16 + L][quad * 8];
    const v8s qf1 = *(v8s*)&Ks[wave * 16 + L][32 + quad * 8];
    v4f oacc[4];
    #pragma unroll
    for (int s = 0; s < 4; s++) {
        v4f a; a[0] = 0.f; a[1] = 0.f; a[2] = 0.f; a[3] = 0.f;
        a = __builtin_amdgcn_mfma_f32_16x16x32_bf16(qf0, *(v8s*)&Sm[s * 16 + L][quad * 8], a, 0, 0, 0);
        a = __builtin_amdgcn_mfma_f32_16x16x32_bf16(qf1, *(v8s*)&Sm[s * 16 + L][32 + quad * 8], a, 0, 0, 0);
        oacc[s] = a;
    }
    {   // scale cross term by gamma^(nrow+1)
        float cf = gpow(g, (float)(n0 + wave * 16 + quad * 4 + 1));
        #pragma unroll
        for (int reg = 0; reg < 4; reg++) {
            #pragma unroll
            for (int s = 0; s < 4; s++) oacc[s][reg] *= cf;
            cf *= g;
        }
    }

    const float* mbase = mask + (size_t)h * Nc * Nc;
    for (int m0 = 0; m0 < Nc; m0 += 64) {
        __syncthreads();
        #pragma unroll
        for (int rep = 0; rep < 2; rep++) {
            int r = (tid >> 3) + rep * 32, ch = (tid & 7) * 8;
            *(uint4*)&Ks[r][ch] = *(const uint4*)(kb + ((size_t)bh * Nc + m0 + r) * Dc + ch);
            *(uint4*)&Vt[r][ch] = *(const uint4*)(vtb + ((size_t)bh * Dc + r) * Nc + m0 + ch);
        }
        __syncthreads();
        // prefetch mask tile values for this wave's band into regs
        float mv[4][4];
        #pragma unroll
        for (int s = 0; s < 4; s++)
            #pragma unroll
            for (int reg = 0; reg < 4; reg++)
                mv[s][reg] = mbase[(size_t)(n0 + wave * 16 + quad * 4 + reg) * Nc + m0 + s * 16 + L];
        // S = Q K^T
        v4f sa[4];
        #pragma unroll
        for (int s = 0; s < 4; s++) {
            v4f a; a[0] = 0.f; a[1] = 0.f; a[2] = 0.f; a[3] = 0.f;
            a = __builtin_amdgcn_mfma_f32_16x16x32_bf16(qf0, *(v8s*)&Ks[s * 16 + L][quad * 8], a, 0, 0, 0);
            a = __builtin_amdgcn_mfma_f32_16x16x32_bf16(qf1, *(v8s*)&Ks[s * 16 + L][32 + quad * 8], a, 0, 0, 0);
            sa[s] = a;
        }
        // masked scores -> bf16 -> LDS (own band; no cross-wave sharing)
        #pragma unroll
        for (int s = 0; s < 4; s++)
            #pragma unroll
            for (int reg = 0; reg < 4; reg++)
                Sm[wave * 16 + quad * 4 + reg][s * 16 + L] = f2bf(sa[s][reg] * mv[s][reg]);
        // O += Sm @ V   (A from own Sm rows, B from V^T)
        v8s af0 = *(v8s*)&Sm[wave * 16 + L][quad * 8];
        v8s af1 = *(v8s*)&Sm[wave * 16 + L][32 + quad * 8];
        #pragma unroll
        for (int s = 0; s < 4; s++) {
            oacc[s] = __builtin_amdgcn_mfma_f32_16x16x32_bf16(af0, *(v8s*)&Vt[s * 16 + L][quad * 8], oacc[s], 0, 0, 0);
            oacc[s] = __builtin_amdgcn_mfma_f32_16x16x32_bf16(af1, *(v8s*)&Vt[s * 16 + L][32 + quad * 8], oacc[s], 0, 0, 0);
        }
    }
    #pragma unroll
    for (int s = 0; s < 4; s++)
        #pragma unroll
        for (int reg = 0; reg < 4; reg++) {
            int n = n0 + wave * 16 + quad * 4 + reg;
            retb[((size_t)b * Nc + n) * Cc + h * 64 + s * 16 + L] = f2bf(oacc[s][reg]);
        }
}

// ---------------------------------------------------------------------------
// K3a: partial state over n-chunk of 256: sum_n g^(2047-n) k_n^T v_n  (bf16 in)
// ---------------------------------------------------------------------------
__global__ __launch_bounds__(256) void state_partial(
    const unsigned short* __restrict__ kg, const unsigned short* __restrict__ vg,
    const float* __restrict__ gamma,
    float* __restrict__ partial)   // [8][B*H*64*64]
{
    __shared__ float Ks[64][65];
    __shared__ float Vs[64][65];
    __shared__ float wdec[64];
    const int chunk = blockIdx.x;
    const int bh = blockIdx.y;
    const int h = bh & 15;
    const int tid = threadIdx.x;
    const int d = tid >> 2;
    const int e0 = (tid & 3) * 16;
    const float g = gamma[h];
    const unsigned short* kb = kg + (size_t)bh * Nc * Dc;
    const unsigned short* vb = vg + (size_t)bh * Nc * Dc;
    float acc[16] = {};
    const int nStart = chunk * 256;
    for (int m0 = nStart; m0 < nStart + 256; m0 += 64) {
        __syncthreads();
        {
            uint4 u0 = *(const uint4*)(kb + (size_t)(m0 + d) * 64 + e0);
            uint4 u1 = *(const uint4*)(kb + (size_t)(m0 + d) * 64 + e0 + 8);
            float f[8];
            unpackb8(u0, f);
            #pragma unroll
            for (int j = 0; j < 8; j++) Ks[d][e0 + j] = f[j];
            unpackb8(u1, f);
            #pragma unroll
            for (int j = 0; j < 8; j++) Ks[d][e0 + 8 + j] = f[j];
            uint4 w0 = *(const uint4*)(vb + (size_t)(m0 + d) * 64 + e0);
            uint4 w1 = *(const uint4*)(vb + (size_t)(m0 + d) * 64 + e0 + 8);
            unpackb8(w0, f);
            #pragma unroll
            for (int j = 0; j < 8; j++) Vs[d][e0 + j] = f[j];
            unpackb8(w1, f);
            #pragma unroll
            for (int j = 0; j < 8; j++) Vs[d][e0 + 8 + j] = f[j];
        }
        if (tid < 64) wdec[tid] = gpow(g, (float)(2047 - (m0 + tid)));
        __syncthreads();
        for (int nn = 0; nn < 64; nn++) {
            float kw = Ks[nn][d] * wdec[nn];
            #pragma unroll
            for (int j = 0; j < 16; j++) acc[j] += kw * Vs[nn][e0 + j];
        }
    }
    float* pp = partial + (size_t)chunk * (Bc * Hc * Dc * Dc)
              + ((size_t)bh * 64 + d) * 64 + e0;
    #pragma unroll
    for (int j = 0; j < 16; j++) pp[j] = acc[j];
}

// K3b: state = sum_chunks partial + state_prev * g^N
__global__ __launch_bounds__(256) void state_reduce(
    const float* __restrict__ partial,
    const float* __restrict__ sprev,
    const float* __restrict__ gamma,
    float* __restrict__ outState)
{
    const int idx = blockIdx.x * 256 + threadIdx.x;
    const int bh = idx >> 12;
    const int h = bh & 15;
    const float g = gamma[h];
    float acc = sprev[idx] * gpow(g, 2048.f);
    #pragma unroll
    for (int c = 0; c < 8; c++) acc += partial[(size_t)c * (Bc * Hc * Dc * Dc) + idx];
    outState[idx] = acc;
}

// ---------------------------------------------------------------------------
// K4: out GEMM via MFMA. A=retb [4096][1024] bf16, B=Wout^T [1024][1024] bf16.
// ---------------------------------------------------------------------------
__global__ __launch_bounds__(256) void out_mfma(
    const unsigned short* __restrict__ A, const unsigned short* __restrict__ Bt,
    const float* __restrict__ bias,
    float* __restrict__ out)   // [4096][1024] f32
{
    __shared__ unsigned short As[64][72];
    __shared__ unsigned short Bs[64][72];
    const int tid = threadIdx.x, wave = tid >> 6, lane = tid & 63;
    const int L = lane & 15, quad = lane >> 4;
    const int row0 = blockIdx.y * 64, col0 = blockIdx.x * 64;
    v4f acc[4];
    #pragma unroll
    for (int s = 0; s < 4; s++) { acc[s][0] = 0.f; acc[s][1] = 0.f; acc[s][2] = 0.f; acc[s][3] = 0.f; }
    for (int k0 = 0; k0 < 1024; k0 += 64) {
        __syncthreads();
        #pragma unroll
        for (int rep = 0; rep < 2; rep++) {
            int r = (tid >> 3) + rep * 32, ch = (tid & 7) * 8;
            *(uint4*)&As[r][ch] = *(const uint4*)(A + (size_t)(row0 + r) * 1024 + k0 + ch);
            *(uint4*)&Bs[r][ch] = *(const uint4*)(Bt + (size_t)(col0 + r) * 1024 + k0 + ch);
        }
        __syncthreads();
        v8s a0 = *(v8s*)&As[wave * 16 + L][quad * 8];
        v8s a1 = *(v8s*)&As[wave * 16 + L][32 + quad * 8];
        #pragma unroll
        for (int s = 0; s < 4; s++) {
            v8s b0 = *(v8s*)&Bs[s * 16 + L][quad * 8];
            v8s b1 = *(v8s*)&Bs[s * 16 + L][32 + quad * 8];
            acc[s] = __builtin_amdgcn_mfma_f32_16x16x32_bf16(a0, b0, acc[s], 0, 0, 0);
            acc[s] = __builtin_amdgcn_mfma_f32_16x16x32_bf16(a1, b1, acc[s], 0, 0, 0);
        }
    }
    #pragma unroll
    for (int s = 0; s < 4; s++) {
        int c = col0 + s * 16 + L;
        float bv = bias[c];
        #pragma unroll
        for (int reg = 0; reg < 4; reg++) {
            int rr = row0 + wave * 16 + quad * 4 + reg;
            out[(size_t)rr * 1024 + c] = acc[s][reg] + bv;
        }
    }
}

extern "C" void kernel_launch(void* const* d_in, const int* in_sizes, int n_in,
                              void* d_out, int out_size, void* d_ws, size_t ws_size,
                              hipStream_t stream) {
    (void)in_sizes; (void)n_in; (void)out_size; (void)ws_size;
    const float* x     = (const float*)d_in[0]; // [B,N,C]
    const float* mask  = (const float*)d_in[1]; // [H,N,N]
    const float* gamma = (const float*)d_in[2]; // [H]
    const float* sprev = (const float*)d_in[3]; // [B,H,D,D]
    const float* Wqkv  = (const float*)d_in[4]; // [C,3C]
    const float* bqkv  = (const float*)d_in[5]; // [3C]
    const float* Wout  = (const float*)d_in[6]; // [C,C]
    const float* bout  = (const float*)d_in[7]; // [C]

    char* W = (char*)d_ws;
    unsigned short* qb   = (unsigned short*)(W);              //  8.4 MB [B,H,N,D]
    unsigned short* kb   = (unsigned short*)(W + 8388608);    //  8.4 MB
    unsigned short* vb   = (unsigned short*)(W + 16777216);   //  8.4 MB
    unsigned short* vtb  = (unsigned short*)(W + 25165824);   //  8.4 MB [B,H,D,N]
    unsigned short* retb = (unsigned short*)(W + 33554432);   //  8.4 MB [B,N,C]
    unsigned short* xb   = (unsigned short*)(W + 41943040);   //  8.4 MB [4096,1024]
    unsigned short* wqt  = (unsigned short*)(W + 50331648);   //  6.3 MB [3072,1024]
    unsigned short* wot  = (unsigned short*)(W + 56623104);   //  2.1 MB [1024,1024]
    float*          part = (float*)        (W + 58720256);    //  4.2 MB

    float* out      = (float*)d_out;                          // [B,N,C]
    float* outState = (float*)d_out + (size_t)Bc * Nc * Cc;   // [B,H,D,D]

    cvt_bf16<<<2048, 256, 0, stream>>>(x, xb, 524288);
    transpose_cvt<<<dim3(48, 16), 256, 0, stream>>>(Wqkv, wqt, 1024, 3072);
    transpose_cvt<<<dim3(16, 16), 256, 0, stream>>>(Wout, wot, 1024, 1024);
    qkv_mfma<<<dim3(48, 64), 256, 0, stream>>>(xb, wqt, bqkv, qb, kb, vb, vtb);
    retention_mfma<<<dim3(32, 32), 256, 0, stream>>>(qb, kb, vtb, mask, gamma, sprev, retb);
    state_partial<<<dim3(8, 32), 256, 0, stream>>>(kb, vb, gamma, part);
    state_reduce<<<512, 256, 0, stream>>>(part, sprev, gamma, outState);
    out_mfma<<<dim3(16, 64), 256, 0, stream>>>(retb, wot, bout, out);
}

// Round 4
// 574.742 us; speedup vs baseline: 5.5235x; 1.0042x over previous
//
#include <hip/hip_runtime.h>
#include <hip/hip_bf16.h>
#include <cstdint>

#define DI __device__ __forceinline__

typedef __attribute__((ext_vector_type(8))) short v8s;   // 8 bf16 (4 VGPRs)
typedef __attribute__((ext_vector_type(4))) float v4f;   // 4 f32 acc

// ---- problem constants ----
constexpr int Bc = 2, Nc = 2048, Cc = 1024, Hc = 16, Dc = 64;

DI float bfbits(uint32_t u) { union { uint32_t i; float f; } c; c.i = u; return c.f; }
DI unsigned short f2bf(float f) {
    union { float f; uint32_t u; } c; c.f = f;
    uint32_t r = c.u + 0x7FFFu + ((c.u >> 16) & 1u);   // RNE
    return (unsigned short)(r >> 16);
}
DI void unpackb8(uint4 u, float* f) {
    f[0] = bfbits(u.x << 16); f[1] = bfbits(u.x & 0xFFFF0000u);
    f[2] = bfbits(u.y << 16); f[3] = bfbits(u.y & 0xFFFF0000u);
    f[4] = bfbits(u.z << 16); f[5] = bfbits(u.z & 0xFFFF0000u);
    f[6] = bfbits(u.w << 16); f[7] = bfbits(u.w & 0xFFFF0000u);
}
DI float gpow(float g, float p) {
    if (p <= 0.f) return 1.f;
    if (g <= 0.f) return 0.f;
    return exp2f(p * log2f(g));
}

// ---------------------------------------------------------------------------
// cvt: f32 -> bf16, 8 elems/thread
// ---------------------------------------------------------------------------
__global__ __launch_bounds__(256) void cvt_bf16(
    const float* __restrict__ in, unsigned short* __restrict__ out, int n8)
{
    int i = blockIdx.x * 256 + threadIdx.x;
    if (i >= n8) return;
    float4 a = ((const float4*)in)[i * 2];
    float4 b = ((const float4*)in)[i * 2 + 1];
    ushort4 r0; r0.x = f2bf(a.x); r0.y = f2bf(a.y); r0.z = f2bf(a.z); r0.w = f2bf(a.w);
    ushort4 r1; r1.x = f2bf(b.x); r1.y = f2bf(b.y); r1.z = f2bf(b.z); r1.w = f2bf(b.w);
    ((ushort4*)out)[i * 2] = r0; ((ushort4*)out)[i * 2 + 1] = r1;
}

// ---------------------------------------------------------------------------
// transpose + cvt: in f32 [R][C] -> out bf16 [C][R].  grid (C/64, R/64)
// ---------------------------------------------------------------------------
__global__ __launch_bounds__(256) void transpose_cvt(
    const float* __restrict__ in, unsigned short* __restrict__ out, int R, int C)
{
    __shared__ float T[64][65];
    const int tid = threadIdx.x;
    const int r0 = blockIdx.y * 64, c0 = blockIdx.x * 64;
    #pragma unroll
    for (int rep = 0; rep < 4; rep++) {
        int row = (tid >> 4) + rep * 16, col = (tid & 15) * 4;
        float4 v = *reinterpret_cast<const float4*>(in + (size_t)(r0 + row) * C + c0 + col);
        T[row][col] = v.x; T[row][col + 1] = v.y; T[row][col + 2] = v.z; T[row][col + 3] = v.w;
    }
    __syncthreads();
    #pragma unroll
    for (int rep = 0; rep < 4; rep++) {
        int ocr = (tid >> 4) + rep * 16, j4 = (tid & 15) * 4;
        ushort4 w;
        w.x = f2bf(T[j4][ocr]);     w.y = f2bf(T[j4 + 1][ocr]);
        w.z = f2bf(T[j4 + 2][ocr]); w.w = f2bf(T[j4 + 3][ocr]);
        *reinterpret_cast<ushort4*>(out + (size_t)(c0 + ocr) * R + r0 + j4) = w;
    }
}

// ---------------------------------------------------------------------------
// K1: qkv GEMM, 128x128 tile, 4 waves (each 64x64). A=[4096][1024] bf16,
// Bt=[3072][1024] bf16. Scatters q(*0.125)/k/v bf16 [B,H,N,D].
// ---------------------------------------------------------------------------
__global__ __launch_bounds__(256) void qkv_mfma(
    const unsigned short* __restrict__ A, const unsigned short* __restrict__ Bt,
    const float* __restrict__ bias,
    unsigned short* __restrict__ q, unsigned short* __restrict__ k,
    unsigned short* __restrict__ v)
{
    __shared__ unsigned short As[128][72];
    __shared__ unsigned short Bs[128][72];
    const int tid = threadIdx.x, wave = tid >> 6, lane = tid & 63;
    const int L = lane & 15, quad = lane >> 4;
    const int wr = (wave >> 1) * 64, wc = (wave & 1) * 64;
    const int row0 = blockIdx.y * 128, col0 = blockIdx.x * 128;
    v4f acc[4][4];
    #pragma unroll
    for (int i = 0; i < 4; i++)
        #pragma unroll
        for (int j = 0; j < 4; j++) { acc[i][j][0]=0.f; acc[i][j][1]=0.f; acc[i][j][2]=0.f; acc[i][j][3]=0.f; }
    for (int k0 = 0; k0 < 1024; k0 += 64) {
        __syncthreads();
        #pragma unroll
        for (int rep = 0; rep < 4; rep++) {
            int r = (tid >> 3) + rep * 32, cg = (tid & 7) * 8;
            *(uint4*)&As[r][cg] = *(const uint4*)(A  + (size_t)(row0 + r) * 1024 + k0 + cg);
            *(uint4*)&Bs[r][cg] = *(const uint4*)(Bt + (size_t)(col0 + r) * 1024 + k0 + cg);
        }
        __syncthreads();
        #pragma unroll
        for (int half = 0; half < 2; half++) {
            v8s af[4], bf[4];
            #pragma unroll
            for (int s = 0; s < 4; s++) {
                af[s] = *(v8s*)&As[wr + s * 16 + L][half * 32 + quad * 8];
                bf[s] = *(v8s*)&Bs[wc + s * 16 + L][half * 32 + quad * 8];
            }
            #pragma unroll
            for (int i = 0; i < 4; i++)
                #pragma unroll
                for (int j = 0; j < 4; j++)
                    acc[i][j] = __builtin_amdgcn_mfma_f32_16x16x32_bf16(af[i], bf[j], acc[i][j], 0, 0, 0);
        }
    }
    const int which = col0 >> 10;   // block-constant (128 | 1024)
    #pragma unroll
    for (int j = 0; j < 4; j++) {
        int c = col0 + wc + j * 16 + L;
        int h = (c & 1023) >> 6, d = c & 63;
        float bv = bias[c];
        #pragma unroll
        for (int i = 0; i < 4; i++) {
            #pragma unroll
            for (int reg = 0; reg < 4; reg++) {
                int rr = row0 + wr + i * 16 + quad * 4 + reg;
                int b = rr >> 11, n = rr & 2047;
                float val = acc[i][j][reg] + bv;
                size_t base = (((size_t)(b * Hc + h)) * Nc + n) * Dc + d;
                if (which == 0)      q[base] = f2bf(val * 0.125f);
                else if (which == 1) k[base] = f2bf(val);
                else                 v[base] = f2bf(val);
            }
        }
    }
}

// ---------------------------------------------------------------------------
// K2: retention via MFMA, both batches fused per block (mask read once).
//   grid (N/64, H). O_b = gamma^(n+1) Q_b sprev_b + sum_m (Q_b K_b^T * mask) V_b
// ---------------------------------------------------------------------------
__global__ __launch_bounds__(256) void retention_mfma(
    const unsigned short* __restrict__ qb, const unsigned short* __restrict__ kb,
    const unsigned short* __restrict__ vb,
    const float* __restrict__ mask, const float* __restrict__ gamma,
    const float* __restrict__ sprev,
    unsigned short* __restrict__ retb)   // [B,N,C] bf16
{
    __shared__ unsigned short K0[64][72], K1[64][72];   // K tiles (also spT at init)
    __shared__ unsigned short V0[64][72], V1[64][72];   // V^T tiles (also Q at init)
    __shared__ unsigned short Sm[64][72];               // masked scores (per-wave bands)
    const int tid = threadIdx.x, wave = tid >> 6, lane = tid & 63;
    const int L = lane & 15, quad = lane >> 4;
    const int h = blockIdx.y;
    const int n0 = blockIdx.x * 64;
    const float g = gamma[h];
    const int bh0 = h, bh1 = Hc + h;

    {   // init stage: Q0->V0, Q1->V1 (row-major), spT0->K0, spT1->K1
        #pragma unroll
        for (int rep = 0; rep < 2; rep++) {
            int r = (tid >> 3) + rep * 32, ch = (tid & 7) * 8;
            *(uint4*)&V0[r][ch] = *(const uint4*)(qb + ((size_t)bh0 * Nc + n0 + r) * Dc + ch);
            *(uint4*)&V1[r][ch] = *(const uint4*)(qb + ((size_t)bh1 * Nc + n0 + r) * Dc + ch);
        }
        int dd = tid >> 2, e0 = (tid & 3) * 16;
        const float* sp0 = sprev + ((size_t)bh0 * 64 + dd) * 64 + e0;
        const float* sp1 = sprev + ((size_t)bh1 * 64 + dd) * 64 + e0;
        #pragma unroll
        for (int j = 0; j < 16; j++) K0[e0 + j][dd] = f2bf(sp0[j]);
        #pragma unroll
        for (int j = 0; j < 16; j++) K1[e0 + j][dd] = f2bf(sp1[j]);
    }
    __syncthreads();
    v8s qf[2][2];
    qf[0][0] = *(v8s*)&V0[wave * 16 + L][quad * 8];
    qf[0][1] = *(v8s*)&V0[wave * 16 + L][32 + quad * 8];
    qf[1][0] = *(v8s*)&V1[wave * 16 + L][quad * 8];
    qf[1][1] = *(v8s*)&V1[wave * 16 + L][32 + quad * 8];
    v4f oacc[2][4];
    #pragma unroll
    for (int b = 0; b < 2; b++) {
        unsigned short (*Kb)[72] = b ? K1 : K0;
        #pragma unroll
        for (int s = 0; s < 4; s++) {
            v4f a; a[0] = 0.f; a[1] = 0.f; a[2] = 0.f; a[3] = 0.f;
            a = __builtin_amdgcn_mfma_f32_16x16x32_bf16(qf[b][0], *(v8s*)&Kb[s * 16 + L][quad * 8], a, 0, 0, 0);
            a = __builtin_amdgcn_mfma_f32_16x16x32_bf16(qf[b][1], *(v8s*)&Kb[s * 16 + L][32 + quad * 8], a, 0, 0, 0);
            oacc[b][s] = a;
        }
    }
    {   // scale cross terms by gamma^(nrow+1) (same for both batches)
        float cf = gpow(g, (float)(n0 + wave * 16 + quad * 4 + 1));
        #pragma unroll
        for (int reg = 0; reg < 4; reg++) {
            #pragma unroll
            for (int b = 0; b < 2; b++)
                #pragma unroll
                for (int s = 0; s < 4; s++) oacc[b][s][reg] *= cf;
            cf *= g;
        }
    }

    const float* mbase = mask + (size_t)h * Nc * Nc;
    const unsigned short* kp0 = kb + (size_t)bh0 * Nc * Dc;
    const unsigned short* kp1 = kb + (size_t)bh1 * Nc * Dc;
    const unsigned short* vp0 = vb + (size_t)bh0 * Nc * Dc;
    const unsigned short* vp1 = vb + (size_t)bh1 * Nc * Dc;

    for (int m0 = 0; m0 < Nc; m0 += 64) {
        __syncthreads();
        {   // K tiles row-major; V tiles transposed into LDS (row=d, col=n_local)
            #pragma unroll
            for (int rep = 0; rep < 2; rep++) {
                int r = (tid >> 3) + rep * 32, ch = (tid & 7) * 8;
                *(uint4*)&K0[r][ch] = *(const uint4*)(kp0 + (size_t)(m0 + r) * Dc + ch);
                *(uint4*)&K1[r][ch] = *(const uint4*)(kp1 + (size_t)(m0 + r) * Dc + ch);
            }
            int n = tid >> 2, d0 = (tid & 3) * 16;
            union { uint4 u[2]; unsigned short s[16]; } tv;
            tv.u[0] = *(const uint4*)(vp0 + (size_t)(m0 + n) * Dc + d0);
            tv.u[1] = *(const uint4*)(vp0 + (size_t)(m0 + n) * Dc + d0 + 8);
            #pragma unroll
            for (int j = 0; j < 16; j++) V0[d0 + j][n] = tv.s[j];
            tv.u[0] = *(const uint4*)(vp1 + (size_t)(m0 + n) * Dc + d0);
            tv.u[1] = *(const uint4*)(vp1 + (size_t)(m0 + n) * Dc + d0 + 8);
            #pragma unroll
            for (int j = 0; j < 16; j++) V1[d0 + j][n] = tv.s[j];
        }
        __syncthreads();
        // mask prefetch — shared between batches
        float mv[4][4];
        #pragma unroll
        for (int s = 0; s < 4; s++)
            #pragma unroll
            for (int reg = 0; reg < 4; reg++)
                mv[s][reg] = mbase[(size_t)(n0 + wave * 16 + quad * 4 + reg) * Nc + m0 + s * 16 + L];
        #pragma unroll
        for (int b = 0; b < 2; b++) {
            unsigned short (*Kb)[72] = b ? K1 : K0;
            unsigned short (*Vb)[72] = b ? V1 : V0;
            v4f sa[4];
            #pragma unroll
            for (int s = 0; s < 4; s++) {
                v4f a; a[0] = 0.f; a[1] = 0.f; a[2] = 0.f; a[3] = 0.f;
                a = __builtin_amdgcn_mfma_f32_16x16x32_bf16(qf[b][0], *(v8s*)&Kb[s * 16 + L][quad * 8], a, 0, 0, 0);
                a = __builtin_amdgcn_mfma_f32_16x16x32_bf16(qf[b][1], *(v8s*)&Kb[s * 16 + L][32 + quad * 8], a, 0, 0, 0);
                sa[s] = a;
            }
            #pragma unroll
            for (int s = 0; s < 4; s++)
                #pragma unroll
                for (int reg = 0; reg < 4; reg++)
                    Sm[wave * 16 + quad * 4 + reg][s * 16 + L] = f2bf(sa[s][reg] * mv[s][reg]);
            v8s af0 = *(v8s*)&Sm[wave * 16 + L][quad * 8];
            v8s af1 = *(v8s*)&Sm[wave * 16 + L][32 + quad * 8];
            #pragma unroll
            for (int s = 0; s < 4; s++) {
                oacc[b][s] = __builtin_amdgcn_mfma_f32_16x16x32_bf16(af0, *(v8s*)&Vb[s * 16 + L][quad * 8], oacc[b][s], 0, 0, 0);
                oacc[b][s] = __builtin_amdgcn_mfma_f32_16x16x32_bf16(af1, *(v8s*)&Vb[s * 16 + L][32 + quad * 8], oacc[b][s], 0, 0, 0);
            }
        }
    }
    #pragma unroll
    for (int b = 0; b < 2; b++)
        #pragma unroll
        for (int s = 0; s < 4; s++)
            #pragma unroll
            for (int reg = 0; reg < 4; reg++) {
                int n = n0 + wave * 16 + quad * 4 + reg;
                retb[((size_t)b * Nc + n) * Cc + h * 64 + s * 16 + L] = f2bf(oacc[b][s][reg]);
            }
}

// ---------------------------------------------------------------------------
// K3a: partial state over n-chunk of 256: sum_n g^(2047-n) k_n^T v_n  (bf16 in)
// ---------------------------------------------------------------------------
__global__ __launch_bounds__(256) void state_partial(
    const unsigned short* __restrict__ kg, const unsigned short* __restrict__ vg,
    const float* __restrict__ gamma,
    float* __restrict__ partial)   // [8][B*H*64*64]
{
    __shared__ float Ks[64][65];
    __shared__ float Vs[64][65];
    __shared__ float wdec[64];
    const int chunk = blockIdx.x;
    const int bh = blockIdx.y;
    const int h = bh & 15;
    const int tid = threadIdx.x;
    const int d = tid >> 2;
    const int e0 = (tid & 3) * 16;
    const float g = gamma[h];
    const unsigned short* kbp = kg + (size_t)bh * Nc * Dc;
    const unsigned short* vbp = vg + (size_t)bh * Nc * Dc;
    float acc[16] = {};
    const int nStart = chunk * 256;
    for (int m0 = nStart; m0 < nStart + 256; m0 += 64) {
        __syncthreads();
        {
            uint4 u0 = *(const uint4*)(kbp + (size_t)(m0 + d) * 64 + e0);
            uint4 u1 = *(const uint4*)(kbp + (size_t)(m0 + d) * 64 + e0 + 8);
            float f[8];
            unpackb8(u0, f);
            #pragma unroll
            for (int j = 0; j < 8; j++) Ks[d][e0 + j] = f[j];
            unpackb8(u1, f);
            #pragma unroll
            for (int j = 0; j < 8; j++) Ks[d][e0 + 8 + j] = f[j];
            uint4 w0 = *(const uint4*)(vbp + (size_t)(m0 + d) * 64 + e0);
            uint4 w1 = *(const uint4*)(vbp + (size_t)(m0 + d) * 64 + e0 + 8);
            unpackb8(w0, f);
            #pragma unroll
            for (int j = 0; j < 8; j++) Vs[d][e0 + j] = f[j];
            unpackb8(w1, f);
            #pragma unroll
            for (int j = 0; j < 8; j++) Vs[d][e0 + 8 + j] = f[j];
        }
        if (tid < 64) wdec[tid] = gpow(g, (float)(2047 - (m0 + tid)));
        __syncthreads();
        for (int nn = 0; nn < 64; nn++) {
            float kw = Ks[nn][d] * wdec[nn];
            #pragma unroll
            for (int j = 0; j < 16; j++) acc[j] += kw * Vs[nn][e0 + j];
        }
    }
    float* pp = partial + (size_t)chunk * (Bc * Hc * Dc * Dc)
              + ((size_t)bh * 64 + d) * 64 + e0;
    #pragma unroll
    for (int j = 0; j < 16; j++) pp[j] = acc[j];
}

// K3b: state = sum_chunks partial + state_prev * g^N
__global__ __launch_bounds__(256) void state_reduce(
    const float* __restrict__ partial,
    const float* __restrict__ sprev,
    const float* __restrict__ gamma,
    float* __restrict__ outState)
{
    const int idx = blockIdx.x * 256 + threadIdx.x;
    const int bh = idx >> 12;
    const int h = bh & 15;
    const float g = gamma[h];
    float acc = sprev[idx] * gpow(g, 2048.f);
    #pragma unroll
    for (int c = 0; c < 8; c++) acc += partial[(size_t)c * (Bc * Hc * Dc * Dc) + idx];
    outState[idx] = acc;
}

// ---------------------------------------------------------------------------
// K4: out GEMM, 128x128 tile. A=retb [4096][1024] bf16, Bt=Wout^T bf16.
// ---------------------------------------------------------------------------
__global__ __launch_bounds__(256) void out_mfma(
    const unsigned short* __restrict__ A, const unsigned short* __restrict__ Bt,
    const float* __restrict__ bias,
    float* __restrict__ out)   // [4096][1024] f32
{
    __shared__ unsigned short As[128][72];
    __shared__ unsigned short Bs[128][72];
    const int tid = threadIdx.x, wave = tid >> 6, lane = tid & 63;
    const int L = lane & 15, quad = lane >> 4;
    const int wr = (wave >> 1) * 64, wc = (wave & 1) * 64;
    const int row0 = blockIdx.y * 128, col0 = blockIdx.x * 128;
    v4f acc[4][4];
    #pragma unroll
    for (int i = 0; i < 4; i++)
        #pragma unroll
        for (int j = 0; j < 4; j++) { acc[i][j][0]=0.f; acc[i][j][1]=0.f; acc[i][j][2]=0.f; acc[i][j][3]=0.f; }
    for (int k0 = 0; k0 < 1024; k0 += 64) {
        __syncthreads();
        #pragma unroll
        for (int rep = 0; rep < 4; rep++) {
            int r = (tid >> 3) + rep * 32, cg = (tid & 7) * 8;
            *(uint4*)&As[r][cg] = *(const uint4*)(A  + (size_t)(row0 + r) * 1024 + k0 + cg);
            *(uint4*)&Bs[r][cg] = *(const uint4*)(Bt + (size_t)(col0 + r) * 1024 + k0 + cg);
        }
        __syncthreads();
        #pragma unroll
        for (int half = 0; half < 2; half++) {
            v8s af[4], bf[4];
            #pragma unroll
            for (int s = 0; s < 4; s++) {
                af[s] = *(v8s*)&As[wr + s * 16 + L][half * 32 + quad * 8];
                bf[s] = *(v8s*)&Bs[wc + s * 16 + L][half * 32 + quad * 8];
            }
            #pragma unroll
            for (int i = 0; i < 4; i++)
                #pragma unroll
                for (int j = 0; j < 4; j++)
                    acc[i][j] = __builtin_amdgcn_mfma_f32_16x16x32_bf16(af[i], bf[j], acc[i][j], 0, 0, 0);
        }
    }
    #pragma unroll
    for (int j = 0; j < 4; j++) {
        int c = col0 + wc + j * 16 + L;
        float bv = bias[c];
        #pragma unroll
        for (int i = 0; i < 4; i++) {
            #pragma unroll
            for (int reg = 0; reg < 4; reg++) {
                int rr = row0 + wr + i * 16 + quad * 4 + reg;
                out[(size_t)rr * 1024 + c] = acc[i][j][reg] + bv;
            }
        }
    }
}

extern "C" void kernel_launch(void* const* d_in, const int* in_sizes, int n_in,
                              void* d_out, int out_size, void* d_ws, size_t ws_size,
                              hipStream_t stream) {
    (void)in_sizes; (void)n_in; (void)out_size; (void)ws_size;
    const float* x     = (const float*)d_in[0]; // [B,N,C]
    const float* mask  = (const float*)d_in[1]; // [H,N,N]
    const float* gamma = (const float*)d_in[2]; // [H]
    const float* sprev = (const float*)d_in[3]; // [B,H,D,D]
    const float* Wqkv  = (const float*)d_in[4]; // [C,3C]
    const float* bqkv  = (const float*)d_in[5]; // [3C]
    const float* Wout  = (const float*)d_in[6]; // [C,C]
    const float* bout  = (const float*)d_in[7]; // [C]

    char* W = (char*)d_ws;
    unsigned short* qb   = (unsigned short*)(W);              //  8.4 MB [B,H,N,D]
    unsigned short* kb   = (unsigned short*)(W + 8388608);    //  8.4 MB
    unsigned short* vb   = (unsigned short*)(W + 16777216);   //  8.4 MB
    unsigned short* retb = (unsigned short*)(W + 33554432);   //  8.4 MB [B,N,C]
    unsigned short* xb   = (unsigned short*)(W + 41943040);   //  8.4 MB [4096,1024]
    unsigned short* wqt  = (unsigned short*)(W + 50331648);   //  6.3 MB [3072,1024]
    unsigned short* wot  = (unsigned short*)(W + 56623104);   //  2.1 MB [1024,1024]
    float*          part = (float*)        (W + 58720256);    //  4.2 MB

    float* out      = (float*)d_out;                          // [B,N,C]
    float* outState = (float*)d_out + (size_t)Bc * Nc * Cc;   // [B,H,D,D]

    cvt_bf16<<<2048, 256, 0, stream>>>(x, xb, 524288);
    transpose_cvt<<<dim3(48, 16), 256, 0, stream>>>(Wqkv, wqt, 1024, 3072);
    transpose_cvt<<<dim3(16, 16), 256, 0, stream>>>(Wout, wot, 1024, 1024);
    qkv_mfma<<<dim3(24, 32), 256, 0, stream>>>(xb, wqt, bqkv, qb, kb, vb);
    retention_mfma<<<dim3(32, 16), 256, 0, stream>>>(qb, kb, vb, mask, gamma, sprev, retb);
    state_partial<<<dim3(8, 32), 256, 0, stream>>>(kb, vb, gamma, part);
    state_reduce<<<512, 256, 0, stream>>>(part, sprev, gamma, outState);
    out_mfma<<<dim3(8, 32), 256, 0, stream>>>(retb, wot, bout, out);
}